// Round 7
// baseline (1151.202 us; speedup 1.0000x reference)
//
#include <hip/hip_runtime.h>
#include <hip/hip_bf16.h>

#define ITER_TIME 32
#define DECAY 0.9f

typedef __attribute__((ext_vector_type(8))) short short8;
typedef __attribute__((ext_vector_type(4))) float f32x4;
typedef unsigned short ushort_t;
typedef unsigned int u32;

// global -> LDS direct DMA, 16B per lane. Dest is wave-uniform base + lane*16.
__device__ __forceinline__ void gload16(const ushort_t* g, ushort_t* l) {
    __builtin_amdgcn_global_load_lds(
        (const __attribute__((address_space(1))) u32*)g,
        (__attribute__((address_space(3))) u32*)l, 16, 0, 0);
}

// ---------------------------------------------------------------------------
// Convert f32 -> bf16 elementwise (for x)
// ---------------------------------------------------------------------------
__global__ void conv_f32_bf16(const float* __restrict__ in,
                              __hip_bfloat16* __restrict__ out, int n) {
    int i = blockIdx.x * 256 + threadIdx.x;
    if (i < n) out[i] = __float2bfloat16(in[i]);
}

// ---------------------------------------------------------------------------
// Fused convert + transpose: f32 in [R][C] -> bf16 out [C][R]
// ---------------------------------------------------------------------------
__global__ void transpose_f32_bf16(const float* __restrict__ in,
                                   __hip_bfloat16* __restrict__ out, int R,
                                   int C) {
    __shared__ float tile[32][33];
    int tx = threadIdx.x, ty = threadIdx.y;
    size_t x = blockIdx.x * 32 + tx;  // col in `in`
    size_t y = blockIdx.y * 32 + ty;  // row in `in`
    tile[ty][tx] = in[y * C + x];
    __syncthreads();
    size_t ox = blockIdx.y * 32 + tx;  // col in `out` (= row in `in`)
    size_t oy = blockIdx.x * 32 + ty;  // row in `out` (= col in `in`)
    out[oy * R + ox] = __float2bfloat16(tile[tx][ty]);
}

// ---------------------------------------------------------------------------
// i_ = x @ W_i with fused t=0 elementwise epilogue:
//   i_ = acc + bias ; u0 = i_ ; act[:,0,:] = u0 ; a0 = relu(u0) (bf16)
// grid (2, 32), block 256, 128x128 tile, K=1024.
// ---------------------------------------------------------------------------
__global__ __launch_bounds__(256)
void gemm_wi(const ushort_t* __restrict__ A,   // [256][1024] bf16
             const ushort_t* __restrict__ BT,  // [4096][1024] bf16
             const float* __restrict__ bias, float* __restrict__ i_,
             float* __restrict__ u, __hip_bfloat16* __restrict__ a0,
             float* __restrict__ act, int K) {
    __shared__ __attribute__((aligned(16))) ushort_t As[2][128 * 64];
    __shared__ __attribute__((aligned(16))) ushort_t Bs[2][128 * 64];

    int m0 = blockIdx.x * 128;
    int by = blockIdx.y;
    const ushort_t* Bsrc = BT + (size_t)by * 128 * K;

    int t = threadIdx.x;
    int wave = t >> 6, lane = t & 63;
    int quad = lane >> 4, l16 = lane & 15;
    int wm = (wave >> 1) * 64, wn = (wave & 1) * 64;

    int lr = lane >> 3;
    int lcol = ((lane & 7) ^ lr) << 3;
    const ushort_t* aBase = A + (size_t)(m0 + wave * 32 + lr) * K + lcol;
    const ushort_t* bBase = Bsrc + (size_t)(wave * 32 + lr) * K + lcol;

    f32x4 acc[4][4];
#pragma unroll
    for (int i = 0; i < 4; i++)
#pragma unroll
        for (int j = 0; j < 4; j++) acc[i][j] = (f32x4){0.f, 0.f, 0.f, 0.f};

    int nt = K >> 6;
    int swz = (l16 & 7) << 3;

    auto stage = [&](int buf, int kk) {
#pragma unroll
        for (int i = 0; i < 4; ++i) {
            gload16(aBase + (size_t)(i * 8) * K + kk,
                    &As[buf][(wave * 4 + i) * 512]);
            gload16(bBase + (size_t)(i * 8) * K + kk,
                    &Bs[buf][(wave * 4 + i) * 512]);
        }
    };

    stage(0, 0);
    __syncthreads();
    int cur = 0;
    for (int it = 0; it < nt; ++it) {
        if (it + 1 < nt) stage(cur ^ 1, (it + 1) * 64);
#pragma unroll
        for (int kstep = 0; kstep < 2; ++kstep) {
            int ko = kstep * 32 + quad * 8;
            int pc = ko ^ swz;
            short8 af[4], bfr[4];
#pragma unroll
            for (int i = 0; i < 4; i++)
                af[i] = *(const short8*)&As[cur][(wm + i * 16 + l16) * 64 + pc];
#pragma unroll
            for (int j = 0; j < 4; j++)
                bfr[j] = *(const short8*)&Bs[cur][(wn + j * 16 + l16) * 64 + pc];
#pragma unroll
            for (int i = 0; i < 4; i++)
#pragma unroll
                for (int j = 0; j < 4; j++)
                    acc[i][j] = __builtin_amdgcn_mfma_f32_16x16x32_bf16(
                        af[i], bfr[j], acc[i][j], 0, 0, 0);
        }
        __syncthreads();
        cur ^= 1;
    }

    // Fused t=0 epilogue. C/D layout: col = lane&15, row = quad*4 + reg.
#pragma unroll
    for (int i = 0; i < 4; i++)
#pragma unroll
        for (int j = 0; j < 4; j++) {
            int gcol = by * 128 + wn + j * 16 + l16;
#pragma unroll
            for (int rr = 0; rr < 4; ++rr) {
                int grow = m0 + wm + i * 16 + quad * 4 + rr;
                size_t p = (size_t)grow * 4096 + gcol;
                float iv = acc[i][j][rr] + bias[gcol];
                i_[p] = iv;
                u[p] = iv;
                __builtin_nontemporal_store(
                    iv, &act[(size_t)grow * (ITER_TIME * 4096) + gcol]);
                float ar = iv > 0.f ? iv : 0.f;
                a0[p] = __float2bfloat16(ar);
            }
        }
}

// ---------------------------------------------------------------------------
// Fully-fused recurrence step (KS=1, no partials, no elem kernel):
//   one block owns a 32x64 output tile of a_t @ [W_r | W_f].
//   W_r tiles (by<64):  u_{t+1} = DECAY*u_t + i_ + r ; act[:,t+1] ; a_{t+1}
//   W_f tiles (by>=64): out[:,t] = f
// Block 256 = 4 waves = 2 k-groups x 2 n-groups. Each wave computes the
// 32x(ng*32..+32) tile over its K-half (2048, nt=32 BK=64 iters); k-halves
// merged via an 8 KB LDS reduction (f32 throughout — precision class of the
// passing split-K versions; NO bf16 partials, round-6 lesson).
// Grid 544 = 512 W_r (8 mt x 64 by) + 32 W_f. LDS 48 KB -> 3 blocks/CU.
// XCD pinning: all 8 mt-siblings of a W_r by-slice land on one XCD
// (by%8 == blk%8) -> 512 KB B-slice HBM-fetched once, L2-hit 7x.
// a_t is read (staged) while a_{t+1} is written -> a double-buffered.
// ONLY_F=1: t=31 tail, W_f tiles only (32 blocks).
// ---------------------------------------------------------------------------
template <int ONLY_F>
__global__ __launch_bounds__(256)
void step_fused(const ushort_t* __restrict__ A,   // a_t [256][4096] bf16
                const ushort_t* __restrict__ BT,  // [4352][4096] bf16 (Wr|Wf)
                const float* __restrict__ i_, float* __restrict__ u,
                __hip_bfloat16* __restrict__ a_out,  // a_{t+1} [256][4096]
                float* __restrict__ out, float* __restrict__ act,
                const int t) {
    const int K = 4096;
    __shared__ __attribute__((aligned(16))) ushort_t As[2][2][32 * 64];  // 16K
    __shared__ __attribute__((aligned(16))) ushort_t Bs[2][2][64 * 64];  // 32K

    int blk = blockIdx.x;
    int mt, by;
    if (ONLY_F) {
        mt = blk & 7;
        by = 64 + (blk >> 3);
    } else if (blk < 512) {
        int xcd = blk & 7, g = blk >> 3;
        by = xcd + 8 * (g & 7);  // by % 8 == xcd for all 8 mt-siblings
        mt = g >> 3;
    } else {
        int idx = blk - 512;
        by = 64 + (idx >> 3);
        mt = idx & 7;
    }
    int m0 = mt * 32;
    const ushort_t* Bsrc = BT + (size_t)by * 64 * K;

    int tid = threadIdx.x;
    int wave = tid >> 6, lane = tid & 63;
    int kg = wave >> 1, ng = wave & 1;
    int quad = lane >> 4, l16 = lane & 15;
    int lr = lane >> 3;                 // row within 8-row staging chunk
    int lcol = ((lane & 7) ^ lr) << 3;  // inverse-swizzled source col

    // Wave (kg,ng) stages: A rows [ng*16, ng*16+16), B rows [ng*32, ng*32+32)
    // of its kg K-half.
    const ushort_t* aBase = A + (size_t)(m0 + ng * 16 + lr) * K + lcol;
    const ushort_t* bBase = Bsrc + (size_t)(ng * 32 + lr) * K + lcol;

    f32x4 acc[2][2];
#pragma unroll
    for (int i = 0; i < 2; i++)
#pragma unroll
        for (int j = 0; j < 2; j++) acc[i][j] = (f32x4){0.f, 0.f, 0.f, 0.f};

    const int k0 = kg * 2048;
    const int nt = 32;  // 2048 / 64
    int swz = (l16 & 7) << 3;

    auto stage = [&](int buf, int kk) {
#pragma unroll
        for (int i = 0; i < 2; ++i)
            gload16(aBase + (size_t)(i * 8) * K + kk,
                    &As[kg][buf][(ng * 2 + i) * 512]);
#pragma unroll
        for (int i = 0; i < 4; ++i)
            gload16(bBase + (size_t)(i * 8) * K + kk,
                    &Bs[kg][buf][(ng * 4 + i) * 512]);
    };

    stage(0, k0);
    __syncthreads();
    int cur = 0;
    for (int it = 0; it < nt; ++it) {
        if (it + 1 < nt) stage(cur ^ 1, k0 + (it + 1) * 64);
#pragma unroll
        for (int kstep = 0; kstep < 2; ++kstep) {
            int ko = kstep * 32 + quad * 8;
            int pc = ko ^ swz;
            short8 af[2], bfr[2];
#pragma unroll
            for (int i = 0; i < 2; i++)
                af[i] = *(const short8*)&As[kg][cur][(i * 16 + l16) * 64 + pc];
#pragma unroll
            for (int j = 0; j < 2; j++)
                bfr[j] = *(const short8*)&Bs[kg][cur]
                                            [(ng * 32 + j * 16 + l16) * 64 + pc];
#pragma unroll
            for (int i = 0; i < 2; i++)
#pragma unroll
                for (int j = 0; j < 2; j++)
                    acc[i][j] = __builtin_amdgcn_mfma_f32_16x16x32_bf16(
                        af[i], bfr[j], acc[i][j], 0, 0, 0);
        }
        __syncthreads();  // drains vmcnt of next stage + publishes buffers
        cur ^= 1;
    }
    // Loop ended with a full barrier: all ds_reads of As/Bs complete.

    // ---- k-half reduction via LDS (reuse As area: need 8 KB of 16 KB) ----
    f32x4* red = (f32x4*)&As[0][0][0];
    if (kg == 1) {
#pragma unroll
        for (int i = 0; i < 2; i++)
#pragma unroll
            for (int j = 0; j < 2; j++)
                red[(size_t)(ng * 64 + lane) * 4 + (i * 2 + j)] = acc[i][j];
    }
    __syncthreads();
    if (kg != 0) return;
#pragma unroll
    for (int i = 0; i < 2; i++)
#pragma unroll
        for (int j = 0; j < 2; j++)
            acc[i][j] += red[(size_t)(ng * 64 + lane) * 4 + (i * 2 + j)];

    // ---- fused elementwise epilogue (kg=0 waves, 128 threads) ------------
    // C/D layout: col = lane&15, row = quad*4 + reg.
    if (by < 64) {
#pragma unroll
        for (int i = 0; i < 2; i++)
#pragma unroll
            for (int j = 0; j < 2; j++) {
                int gcol = by * 64 + ng * 32 + j * 16 + l16;
#pragma unroll
                for (int rr = 0; rr < 4; ++rr) {
                    int grow = m0 + i * 16 + quad * 4 + rr;
                    size_t p = (size_t)grow * 4096 + gcol;
                    float un = DECAY * u[p] + i_[p] + acc[i][j][rr];
                    u[p] = un;
                    __builtin_nontemporal_store(
                        un, &act[(size_t)grow * (ITER_TIME * 4096) +
                                 (size_t)(t + 1) * 4096 + gcol]);
                    float ar = un > 0.f ? un : 0.f;
                    a_out[p] = __float2bfloat16(ar);
                }
            }
    } else {
#pragma unroll
        for (int i = 0; i < 2; i++)
#pragma unroll
            for (int j = 0; j < 2; j++) {
                int c2 = (by - 64) * 64 + ng * 32 + j * 16 + l16;
#pragma unroll
                for (int rr = 0; rr < 4; ++rr) {
                    int grow = m0 + i * 16 + quad * 4 + rr;
                    __builtin_nontemporal_store(
                        acc[i][j][rr],
                        &out[(size_t)grow * (ITER_TIME * 256) +
                             (size_t)t * 256 + c2]);
                }
            }
    }
}

// ---------------------------------------------------------------------------
// Workspace layout (54.5 MB peak):
//   BT   0x0000000  34 MB  bf16 [4352][4096]  (W_r^T | W_f^T)
//   i_   0x2200000   4 MB  f32 [256][4096]  (biased drive)
//   u    0x2600000   4 MB  f32 [256][4096]
//   a0   0x2A00000   2 MB  bf16 [256][4096]
//   a1   0x2C00000   2 MB  bf16 [256][4096]
//   WiT  0x2E00000   8 MB  bf16 [4096][1024]  (setup transient)
//   xb   0x3600000  .5 MB  bf16 [256][1024]   (setup transient)
// ---------------------------------------------------------------------------
extern "C" void kernel_launch(void* const* d_in, const int* in_sizes, int n_in,
                              void* d_out, int out_size, void* d_ws,
                              size_t ws_size, hipStream_t stream) {
    const float* x = (const float*)d_in[0];    // [256][1024] f32
    const float* Wi = (const float*)d_in[1];   // [1024][4096] f32
    const float* bb = (const float*)d_in[2];   // [4096] f32
    const float* Wr = (const float*)d_in[3];   // [4096][4096] f32
    const float* Wf = (const float*)d_in[4];   // [4096][256] f32

    float* out = (float*)d_out;                        // [256][32][256]
    float* act = out + (size_t)256 * ITER_TIME * 256;  // [256][32][4096]

    char* ws = (char*)d_ws;
    __hip_bfloat16* BT = (__hip_bfloat16*)(ws + 0x0);
    float* i_ = (float*)(ws + 0x2200000);
    float* u = (float*)(ws + 0x2600000);
    __hip_bfloat16* a0 = (__hip_bfloat16*)(ws + 0x2A00000);
    __hip_bfloat16* a1 = (__hip_bfloat16*)(ws + 0x2C00000);
    __hip_bfloat16* WiT = (__hip_bfloat16*)(ws + 0x2E00000);  // transient
    __hip_bfloat16* xb = (__hip_bfloat16*)(ws + 0x3600000);   // transient

    conv_f32_bf16<<<1024, 256, 0, stream>>>(x, xb, 256 * 1024);
    dim3 tb(32, 32);
    transpose_f32_bf16<<<dim3(128, 32), tb, 0, stream>>>(Wi, WiT, 1024, 4096);
    transpose_f32_bf16<<<dim3(128, 128), tb, 0, stream>>>(Wr, BT, 4096, 4096);
    transpose_f32_bf16<<<dim3(8, 128), tb, 0, stream>>>(
        Wf, BT + (size_t)4096 * 4096, 4096, 256);

    // i_ = x @ W_i + b, fused u0/act0/a0 epilogue
    gemm_wi<<<dim3(2, 32), 256, 0, stream>>>((const ushort_t*)xb,
                                             (const ushort_t*)WiT, bb, i_, u,
                                             a0, act, 1024);

    // One fused kernel per step: reads a[t&1], writes a[(t+1)&1]/u/act/out.
    for (int t = 0; t < ITER_TIME - 1; ++t) {
        const ushort_t* ain = (const ushort_t*)((t & 1) ? a1 : a0);
        __hip_bfloat16* aout = (t & 1) ? a0 : a1;
        step_fused<0><<<544, 256, 0, stream>>>(ain, (const ushort_t*)BT, i_, u,
                                               aout, out, act, t);
    }
    // t = 31: only W_f tiles (out[:,31,:]); no further u/a needed.
    step_fused<1><<<32, 256, 0, stream>>>((const ushort_t*)a1,
                                          (const ushort_t*)BT, i_, u, a0, out,
                                          act, ITER_TIME - 1);
}